// Round 13
// baseline (8078.075 us; speedup 1.0000x reference)
//
#include <hip/hip_runtime.h>

// Problem dims (fixed)
constexpr int Bb = 32;    // batch
constexpr int Tt = 1024;  // time steps
constexpr int Hh = 1024;  // hidden
constexpr int Di = 512;   // input dim
constexpr int Do = 512;   // output dim
constexpr int BbHh = Bb * Hh;

using bf16x8 = __attribute__((ext_vector_type(8))) short;
using f32x4  = __attribute__((ext_vector_type(4))) float;

__device__ __forceinline__ f32x4 mfma16(bf16x8 a, bf16x8 b, f32x4 c) {
  return __builtin_amdgcn_mfma_f32_16x16x32_bf16(a, b, c, 0, 0, 0);
}
__device__ __forceinline__ unsigned short f2bf(float f) {
  unsigned u = __builtin_bit_cast(unsigned, f);
  u += 0x7FFFu + ((u >> 16) & 1u);
  return (unsigned short)(u >> 16);
}
__device__ __forceinline__ float bf2f(unsigned short h) {
  unsigned u = ((unsigned)h) << 16;
  return __builtin_bit_cast(float, u);
}

// ---------------- fp32 -> bf16 bulk convert (for Wh) ----------------
__global__ __launch_bounds__(256) void cvt4_kernel(const float* __restrict__ s,
                                                   unsigned short* __restrict__ d) {
  int i = (blockIdx.x * 256 + threadIdx.x) * 4;
  float4 v = *(const float4*)(s + i);
  ushort4 u = { f2bf(v.x), f2bf(v.y), f2bf(v.z), f2bf(v.w) };
  *(ushort4*)(d + i) = u;
}

// ---------------- GEMM: C[m][n] = sum_k A[m][k] * Bw[n][k] (+bias) ----------------
template <int MODE>
__global__ __launch_bounds__(256)
void gemm_kernel(const void* __restrict__ Ap, const float* __restrict__ Bw,
                 const float* __restrict__ bias1, const float* __restrict__ bias2,
                 void* __restrict__ Cp) {
  constexpr int K = (MODE == 0) ? Di : Hh;
  constexpr int BM = 64, BN = 64, BK = 64;
  __shared__ unsigned short As[BM][80];
  __shared__ unsigned short Bs[BN][80];

  const int m0 = blockIdx.x * BM;
  const int n0 = blockIdx.y * BN;
  const int tid = threadIdx.x;
  const int lane = tid & 63;
  const int wave = tid >> 6;
  const int wm = (wave & 1) * 32;
  const int wn = (wave >> 1) * 32;
  const int fr = lane & 15;
  const int kg = lane >> 4;

  f32x4 acc[2][2] = {};

  const int srow = tid >> 2;          // 0..63
  const int scb  = (tid & 3) * 16;    // 0,16,32,48

  for (int k0 = 0; k0 < K; k0 += BK) {
    if constexpr (MODE == 0) {
      const float* a = (const float*)Ap + (size_t)(m0 + srow) * K + k0 + scb;
#pragma unroll
      for (int q = 0; q < 4; ++q) {
        float4 v = ((const float4*)a)[q];
        ushort4 u = { f2bf(v.x), f2bf(v.y), f2bf(v.z), f2bf(v.w) };
        *(ushort4*)&As[srow][scb + q * 4] = u;
      }
    } else {
      const unsigned short* a = (const unsigned short*)Ap + (size_t)(m0 + srow) * K + k0 + scb;
      *(uint4*)&As[srow][scb]     = ((const uint4*)a)[0];
      *(uint4*)&As[srow][scb + 8] = ((const uint4*)a)[1];
    }
    {
      const float* b = Bw + (size_t)(n0 + srow) * K + k0 + scb;
#pragma unroll
      for (int q = 0; q < 4; ++q) {
        float4 v = ((const float4*)b)[q];
        ushort4 u = { f2bf(v.x), f2bf(v.y), f2bf(v.z), f2bf(v.w) };
        *(ushort4*)&Bs[srow][scb + q * 4] = u;
      }
    }
    __syncthreads();

#pragma unroll
    for (int kk = 0; kk < 2; ++kk) {
      const int kb = kk * 32 + kg * 8;
      bf16x8 af[2], bfr[2];
      af[0]  = *(const bf16x8*)&As[wm + fr][kb];
      af[1]  = *(const bf16x8*)&As[wm + 16 + fr][kb];
      bfr[0] = *(const bf16x8*)&Bs[wn + fr][kb];
      bfr[1] = *(const bf16x8*)&Bs[wn + 16 + fr][kb];
#pragma unroll
      for (int i = 0; i < 2; ++i)
#pragma unroll
        for (int j = 0; j < 2; ++j)
          acc[i][j] = mfma16(af[i], bfr[j], acc[i][j]);
    }
    __syncthreads();
  }

#pragma unroll
  for (int i = 0; i < 2; ++i) {
#pragma unroll
    for (int j = 0; j < 2; ++j) {
      const int n = n0 + wn + j * 16 + fr;
      float bv;
      if constexpr (MODE == 0) bv = bias1[n] + bias2[n];
      else                     bv = bias1[n];
#pragma unroll
      for (int q = 0; q < 4; ++q) {
        const int m = m0 + wm + i * 16 + kg * 4 + q;
        float v = acc[i][j][q] + bv;
        if constexpr (MODE == 0) {
          int bb = m >> 10, ttt = m & 1023;
          ((unsigned short*)Cp)[((size_t)ttt * Bb + bb) * Hh + n] = f2bf(v);
        } else {
          int bb = m & 31, ttt = m >> 5;
          ((float*)Cp)[((size_t)bb * Tt + ttt) * Do + n] = v;
        }
      }
    }
  }
}

// ---------------- sequential scan: barrier-free per-wave dataflow (spill-proof) ----
// 32 blocks x 256 threads (4 waves), 1 block/CU. Group g = blockIdx>>4 (16 batches),
// r = blockIdx&15. Wave W = r*4+wave owns 16 h-rows. No LDS, no __syncthreads.
// Sync: per-wave flag[g][W] = steps completed (release: vmcnt(0) then sc0sc1 store).
// Panel loaded in TWO passes of 16 dwordx4 (pa[16] reused) so peak live regs stay
// ~236 << 512 (launch_bounds 256,1) — R12's ~300 live likely spilled, and a spill
// of an in-flight async asm-load output reads the reg before vmcnt retires it.
// Counted vmcnt uses plain asm + sched_barrier(0) (rule #18, R11 fix).
// WAR-safe: write buf[(t+1)&1] gated on flags>=t. Spins BOUNDED: never a hang.
__global__ __launch_bounds__(256, 1)
void scan_kernel(const unsigned short* __restrict__ Whb,  // bf16 [H][H]
                 const unsigned short* __restrict__ xp,   // bf16 [T][B][H]
                 unsigned short* __restrict__ hist,       // bf16 [T][B][H]
                 unsigned short* __restrict__ hbuf,       // bf16 [2][B][H]
                 unsigned* __restrict__ flags) {          // [2][64]
  const int tid = threadIdx.x;
  const int g = blockIdx.x >> 4;
  const int r = blockIdx.x & 15;
  const int wave = tid >> 6;
  const int lane = tid & 63;
  const int nloc = lane & 15;
  const int kgrp = lane >> 4;
  const int W = r * 4 + wave;              // 0..63 within group
  const int hrow = W * 16 + nloc;          // this lane's h output row
  const int gb0 = g * 16;

  // preload Wh fragments via opaque asm loads (proven-safe R10 form)
  bf16x8 wf[32];
  {
    const unsigned short* wb = Whb + (size_t)hrow * Hh + kgrp * 8;
#pragma unroll
    for (int kk = 0; kk < 32; kk += 8) {
      const unsigned short* p = wb + kk * 32;
      asm volatile(
          "global_load_dwordx4 %0, %8, off\n\t"
          "global_load_dwordx4 %1, %8, off offset:64\n\t"
          "global_load_dwordx4 %2, %8, off offset:128\n\t"
          "global_load_dwordx4 %3, %8, off offset:192\n\t"
          "global_load_dwordx4 %4, %8, off offset:256\n\t"
          "global_load_dwordx4 %5, %8, off offset:320\n\t"
          "global_load_dwordx4 %6, %8, off offset:384\n\t"
          "global_load_dwordx4 %7, %8, off offset:448\n\t"
          "s_waitcnt vmcnt(0)"
          : "=&v"(wf[kk + 0]), "=&v"(wf[kk + 1]), "=&v"(wf[kk + 2]), "=&v"(wf[kk + 3]),
            "=&v"(wf[kk + 4]), "=&v"(wf[kk + 5]), "=&v"(wf[kk + 6]), "=&v"(wf[kk + 7])
          : "v"(p)
          : "memory");
    }
  }

  unsigned* fbase = flags + g * 64;
  const unsigned* fp = fbase + lane;       // lane i watches flag i

  for (int t = 0; t < Tt; ++t) {
    const unsigned short* hrd = hbuf + (size_t)(t & 1) * BbHh;        // h^{t-1}
    unsigned short* hwr = hbuf + (size_t)((t + 1) & 1) * BbHh;        // h^{t}

    // xp prefetch (normal cached; drained by the spin's vmcnt(0))
    unsigned short xpv[4];
    const size_t xb = (size_t)t * BbHh + hrow;
#pragma unroll
    for (int i = 0; i < 4; ++i) xpv[i] = xp[xb + (size_t)(gb0 + kgrp * 4 + i) * Hh];

    // spin: all 64 waves of this group have completed step t-1 (flag >= t)
    {
      unsigned fl;
      int tries = 4096;
      do {
        asm volatile("global_load_dword %0, %1, off sc0 sc1\n\ts_waitcnt vmcnt(0)"
                     : "=&v"(fl) : "v"(fp) : "memory");
      } while (__any(fl < (unsigned)t) && --tries);
    }

    // A-panel: lane (nloc,kgrp) needs batch nloc, fragment kk at byte offset kk*64.
    const unsigned short* abase = hrd + (size_t)(gb0 + nloc) * Hh + kgrp * 8;
    f32x4 acc0 = {0.f, 0.f, 0.f, 0.f}, acc1 = {0.f, 0.f, 0.f, 0.f};
    f32x4 acc2 = {0.f, 0.f, 0.f, 0.f}, acc3 = {0.f, 0.f, 0.f, 0.f};
    uint4 pa[16];

#define ISSUE4(I, O0, O1, O2, O3)                                             \
    asm volatile(                                                             \
        "global_load_dwordx4 %0, %4, off offset:" #O0 " sc0 sc1\n\t"          \
        "global_load_dwordx4 %1, %4, off offset:" #O1 " sc0 sc1\n\t"          \
        "global_load_dwordx4 %2, %4, off offset:" #O2 " sc0 sc1\n\t"          \
        "global_load_dwordx4 %3, %4, off offset:" #O3 " sc0 sc1"              \
        : "=&v"(pa[I]), "=&v"(pa[I + 1]), "=&v"(pa[I + 2]), "=&v"(pa[I + 3])  \
        : "v"(abase) : "memory")

#define CONSUME4(I, KB, N)                                                    \
    asm volatile("s_waitcnt vmcnt(" #N ")" ::: "memory");                     \
    __builtin_amdgcn_sched_barrier(0);                                        \
    acc0 = mfma16(__builtin_bit_cast(bf16x8, pa[I]),     wf[KB],     acc0);   \
    acc1 = mfma16(__builtin_bit_cast(bf16x8, pa[I + 1]), wf[KB + 1], acc1);   \
    acc2 = mfma16(__builtin_bit_cast(bf16x8, pa[I + 2]), wf[KB + 2], acc2);   \
    acc3 = mfma16(__builtin_bit_cast(bf16x8, pa[I + 3]), wf[KB + 3], acc3);   \
    __builtin_amdgcn_sched_barrier(0)

    // ---- pass A: fragments 0..15 (byte offsets 0..960), 16 in flight ----
    ISSUE4(0,    0,   64,  128,  192);
    ISSUE4(4,  256,  320,  384,  448);
    ISSUE4(8,  512,  576,  640,  704);
    ISSUE4(12, 768,  832,  896,  960);
    CONSUME4(0,  0, 12);
    CONSUME4(4,  4,  8);
    CONSUME4(8,  8,  4);
    CONSUME4(12, 12, 0);

    // ---- pass B: fragments 16..31 (byte offsets 1024..1984), pa[] reused ----
    ISSUE4(0,  1024, 1088, 1152, 1216);
    ISSUE4(4,  1280, 1344, 1408, 1472);
    ISSUE4(8,  1536, 1600, 1664, 1728);
    ISSUE4(12, 1792, 1856, 1920, 1984);
    CONSUME4(0,  16, 12);
    CONSUME4(4,  20,  8);
    CONSUME4(8,  24,  4);
    CONSUME4(12, 28, 0);
#undef ISSUE4
#undef CONSUME4
    f32x4 acc = (acc0 + acc1) + (acc2 + acc3);

    // epilogue: sigmoid, publish h^t (sc0sc1) first, record history (cached)
    const size_t tb = (size_t)t * BbHh;
#pragma unroll
    for (int i = 0; i < 4; ++i) {
      const int mb = gb0 + kgrp * 4 + i;
      float pre = acc[i] + bf2f(xpv[i]);
      float h = 1.0f / (1.0f + __expf(-pre));
      unsigned short hb = f2bf(h);
      asm volatile("global_store_short %0, %1, off sc0 sc1"
                   :: "v"(hwr + (size_t)mb * Hh + hrow), "v"((unsigned)hb) : "memory");
      hist[tb + (size_t)mb * Hh + hrow] = hb;
    }

    // release: drain all stores, then post this wave's flag
    asm volatile("s_waitcnt vmcnt(0)" ::: "memory");
    if (lane == 0)
      asm volatile("global_store_dword %0, %1, off sc0 sc1"
                   :: "v"(fbase + W), "v"((unsigned)(t + 1)) : "memory");
  }
}

// ---------------- launch ----------------
extern "C" void kernel_launch(void* const* d_in, const int* in_sizes, int n_in,
                              void* d_out, int out_size, void* d_ws, size_t ws_size,
                              hipStream_t stream) {
  const float* x    = (const float*)d_in[0];
  const float* Wh_w = (const float*)d_in[1];
  const float* Wh_b = (const float*)d_in[2];
  const float* Wx_w = (const float*)d_in[3];
  const float* Wx_b = (const float*)d_in[4];
  const float* Wy_w = (const float*)d_in[5];
  const float* Wy_b = (const float*)d_in[6];

  char* ws = (char*)d_ws;
  constexpr size_t XP_OFF   = 0;                                     // bf16 [T][B][H] = 64 MiB
  constexpr size_t HIST_OFF = XP_OFF   + (size_t)Tt * Bb * Hh * 2;   // 64 MiB
  constexpr size_t WH_OFF   = HIST_OFF + (size_t)Tt * Bb * Hh * 2;   // 2 MiB
  constexpr size_t HBUF_OFF = WH_OFF   + (size_t)Hh * Hh * 2;        // 128 KiB
  constexpr size_t FLG_OFF  = HBUF_OFF + (size_t)2 * BbHh * 2;       // 512 B

  unsigned short* xp    = (unsigned short*)(ws + XP_OFF);
  unsigned short* hist  = (unsigned short*)(ws + HIST_OFF);
  unsigned short* whb   = (unsigned short*)(ws + WH_OFF);
  unsigned short* hbuf  = (unsigned short*)(ws + HBUF_OFF);
  unsigned*       flags = (unsigned*)(ws + FLG_OFF);

  // zero h ping-pong + flags every call (graph replays; nothing persists)
  hipMemsetAsync(ws + HBUF_OFF, 0, (size_t)2 * BbHh * 2 + 512, stream);

  // Wh fp32 -> bf16
  cvt4_kernel<<<dim3((Hh * Hh) / (256 * 4)), dim3(256), 0, stream>>>(Wh_w, whb);

  // xp = x @ Wx^T + Wx_b + Wh_b   (stored [T][B][H] bf16)
  gemm_kernel<0><<<dim3((Bb * Tt) / 64, Hh / 64), dim3(256), 0, stream>>>(
      (const void*)x, Wx_w, Wx_b, Wh_b, (void*)xp);

  // sequential scan (cooperative; fallback to plain launch if coop refused —
  // 32 blocks on 256 CUs co-schedule anyway and all spins are bounded)
  {
    void* sargs[5] = { (void*)&whb, (void*)&xp, (void*)&hist, (void*)&hbuf, (void*)&flags };
    hipError_t ce = hipLaunchCooperativeKernel((const void*)scan_kernel, dim3(32), dim3(256),
                                               sargs, 0, stream);
    if (ce != hipSuccess) {
      scan_kernel<<<dim3(32), dim3(256), 0, stream>>>(whb, xp, hist, hbuf, flags);
    }
  }

  // out = hist @ Wy^T + Wy_b  (fp32 [B][T][Do])
  gemm_kernel<1><<<dim3((Bb * Tt) / 64, Do / 64), dim3(256), 0, stream>>>(
      (const void*)hist, Wy_w, Wy_b, nullptr, d_out);
}